// Round 1
// baseline (5304.942 us; speedup 1.0000x reference)
//
#include <hip/hip_runtime.h>

#define NN 50000
#define NE 30000
#define NT 8
#define HH 128
#define NB 64
#define CONT 96
#define EPB 512
#define MT 16

// ---------------------------------------------------------------- init
__global__ __launch_bounds__(256) void init_kernel(
    const int* __restrict__ cid, const int* __restrict__ tg,
    const float* __restrict__ ctab, const float* __restrict__ ttab,
    float* __restrict__ initb, float* __restrict__ states)
{
  int i = blockIdx.x * 256 + threadIdx.x;
  if (i >= NN * HH) return;
  int n = i >> 7, d = i & 127;
  float v;
  if (d < CONT) v = ctab[(size_t)cid[n] * CONT + d];
  else          v = ttab[(size_t)tg[n] * 32 + (d - CONT)];
  initb[i]  = v;
  states[i] = v;
}

// ---------------------------------------------------------------- messages
// block = (edge chunk, type). W[t] staged in LDS (64KB). One wave per edge:
// lane computes output dims {lane, lane+64}; src row broadcast via shfl.
__global__ __launch_bounds__(256) void msg_kernel(
    const float* __restrict__ states, const int* __restrict__ esrc,
    const int* __restrict__ etgt, const float* __restrict__ Wall,
    const float* __restrict__ ball, float* __restrict__ agg, int layer)
{
  __shared__ float Wl[HH * HH];  // 64KB
  const int t = blockIdx.y;
  const float* W = Wall + (size_t)(layer * NT + t) * HH * HH;
  for (int i = threadIdx.x * 4; i < HH * HH; i += 256 * 4)
    *(float4*)&Wl[i] = *(const float4*)&W[i];
  const int lane = threadIdx.x & 63;
  const int wv   = threadIdx.x >> 6;
  const float b0 = ball[(layer * NT + t) * HH + lane];
  const float b1 = ball[(layer * NT + t) * HH + lane + 64];
  __syncthreads();
  const int e1 = min((int)((blockIdx.x + 1) * EPB), NE);
  for (int e = blockIdx.x * EPB + wv; e < e1; e += 4) {
    const int src = esrc[t * NE + e];
    const int tgt = etgt[t * NE + e];
    const float s0 = states[(size_t)src * HH + lane];
    const float s1 = states[(size_t)src * HH + lane + 64];
    float a0 = b0, a1 = b1;
#pragma unroll 8
    for (int h = 0; h < 64; ++h) {
      float sv = __shfl(s0, h, 64);
      a0 += sv * Wl[h * HH + lane];
      a1 += sv * Wl[h * HH + lane + 64];
    }
#pragma unroll 8
    for (int h = 0; h < 64; ++h) {
      float sv = __shfl(s1, h, 64);
      a0 += sv * Wl[(h + 64) * HH + lane];
      a1 += sv * Wl[(h + 64) * HH + lane + 64];
    }
    atomicAdd(&agg[(size_t)tgt * HH + lane], a0);
    atomicAdd(&agg[(size_t)tgt * HH + lane + 64], a1);
  }
}

// ---------------------------------------------------------------- fused GRU
// 384 threads: thread owns gate column d in [0,384). 16 nodes per block.
// Tiles (xaT/xbT/hT, transposed [128][16]) aliased with gi/gh stash.
// PyTorch gate order r,z,n: h' = (1-z)*tanh(i_n + r*h_n) + z*h.
template <int TWOK>
__global__ __launch_bounds__(384) void gru_kernel(
    const float* __restrict__ xa, const float* __restrict__ xb,
    const float* __restrict__ Wih, const float* __restrict__ Wib,
    const float* __restrict__ Whh,
    const float* __restrict__ bih, const float* __restrict__ bhh,
    float* __restrict__ states)
{
  __shared__ float smem[MT * 384 * 2];  // 48KB
  float* xaT = smem;                // [128][MT]
  float* xbT = smem + HH * MT;
  float* hT  = smem + 2 * HH * MT;
  float* gi_s = smem;               // [MT][384]  (aliases tiles, used later)
  float* gh_s = smem + MT * 384;

  const int nb  = blockIdx.x * MT;
  const int tid = threadIdx.x;

  for (int i = tid; i < HH * MT; i += 384) {
    int m = i >> 7, k = i & 127;
    xaT[k * MT + m] = xa[(size_t)(nb + m) * HH + k];
    hT [k * MT + m] = states[(size_t)(nb + m) * HH + k];
    if (TWOK) xbT[k * MT + m] = xb[(size_t)(nb + m) * HH + k];
  }
  __syncthreads();

  float acc_i[MT], acc_h[MT];
  const float bi = bih[tid], bh = bhh[tid];
#pragma unroll
  for (int m = 0; m < MT; ++m) { acc_i[m] = bi; acc_h[m] = bh; }

  for (int k = 0; k < HH; ++k) {
    const float wa = Wih[k * 384 + tid];
    const float wh = Whh[k * 384 + tid];
    float wb = 0.f;
    if (TWOK) wb = Wib[k * 384 + tid];
#pragma unroll
    for (int m = 0; m < MT; ++m) {
      acc_i[m] += xaT[k * MT + m] * wa;
      acc_h[m] += hT [k * MT + m] * wh;
      if (TWOK) acc_i[m] += xbT[k * MT + m] * wb;
    }
  }
  __syncthreads();  // tiles no longer needed; reuse LDS for gate stash
#pragma unroll
  for (int m = 0; m < MT; ++m) {
    gi_s[m * 384 + tid] = acc_i[m];
    gh_s[m * 384 + tid] = acc_h[m];
  }
  __syncthreads();

  if (tid < HH) {
    for (int m = 0; m < MT; ++m) {
      const float ir  = gi_s[m * 384 + tid];
      const float iz  = gi_s[m * 384 + tid + 128];
      const float inn = gi_s[m * 384 + tid + 256];
      const float hr  = gh_s[m * 384 + tid];
      const float hz  = gh_s[m * 384 + tid + 128];
      const float hn  = gh_s[m * 384 + tid + 256];
      const float r = 1.f / (1.f + __expf(-(ir + hr)));
      const float z = 1.f / (1.f + __expf(-(iz + hz)));
      const float nn = tanhf(inn + r * hn);
      const float hcur = states[(size_t)(nb + m) * HH + tid];
      states[(size_t)(nb + m) * HH + tid] = (1.f - z) * nn + z * hcur;
    }
  }
}

// ---------------------------------------------------------------- readout
// wave per node: g = sigmoid(dot(s, rw) + rb); atomicAdd g*s into out[ex].
__global__ __launch_bounds__(256) void readout_kernel(
    const float* __restrict__ states, const int* __restrict__ n2e,
    const float* __restrict__ rw, const float* __restrict__ rb,
    float* __restrict__ out, int coff)
{
  const int lane = threadIdx.x & 63;
  const int n = blockIdx.x * 4 + (threadIdx.x >> 6);
  if (n >= NN) return;
  const float s0 = states[(size_t)n * HH + lane];
  const float s1 = states[(size_t)n * HH + lane + 64];
  float p = s0 * rw[lane] + s1 * rw[lane + 64];
#pragma unroll
  for (int o = 32; o; o >>= 1) p += __shfl_xor(p, o, 64);
  const float g = 1.f / (1.f + __expf(-(p + rb[0])));
  const int ex = n2e[n];
  atomicAdd(&out[(size_t)ex * (2 * HH) + coff + lane], g * s0);
  atomicAdd(&out[(size_t)ex * (2 * HH) + coff + lane + 64], g * s1);
}

// ---------------------------------------------------------------- launch
extern "C" void kernel_launch(void* const* d_in, const int* in_sizes, int n_in,
                              void* d_out, int out_size, void* d_ws, size_t ws_size,
                              hipStream_t stream)
{
  const int*   cid   = (const int*)d_in[0];
  const int*   tg    = (const int*)d_in[1];
  const int*   esrc  = (const int*)d_in[2];
  const int*   etgt  = (const int*)d_in[3];
  const int*   n2e   = (const int*)d_in[4];
  const float* ctab  = (const float*)d_in[5];
  const float* ttab  = (const float*)d_in[6];
  const float* msgW  = (const float*)d_in[7];
  const float* msgb  = (const float*)d_in[8];
  const float* g0Wih = (const float*)d_in[9];
  const float* g0Whh = (const float*)d_in[10];
  const float* g0bih = (const float*)d_in[11];
  const float* g0bhh = (const float*)d_in[12];
  const float* g1Wih = (const float*)d_in[13];
  const float* g1Whh = (const float*)d_in[14];
  const float* g1bih = (const float*)d_in[15];
  const float* g1bhh = (const float*)d_in[16];
  const float* r1w   = (const float*)d_in[17];
  const float* r1b   = (const float*)d_in[18];
  const float* r2w   = (const float*)d_in[19];
  const float* r2b   = (const float*)d_in[20];

  float* out    = (float*)d_out;
  float* states = (float*)d_ws;
  float* initb  = states + (size_t)NN * HH;
  float* agg    = initb  + (size_t)NN * HH;

  hipMemsetAsync(d_out, 0, (size_t)NB * 2 * HH * sizeof(float), stream);
  init_kernel<<<(NN * HH + 255) / 256, 256, 0, stream>>>(cid, tg, ctab, ttab, initb, states);

  dim3 mgrid((NE + EPB - 1) / EPB, NT);
  for (int s = 0; s < 3; ++s) {
    hipMemsetAsync(agg, 0, (size_t)NN * HH * sizeof(float), stream);
    msg_kernel<<<mgrid, 256, 0, stream>>>(states, esrc, etgt, msgW, msgb, agg, 0);
    gru_kernel<0><<<NN / MT, 384, 0, stream>>>(agg, nullptr, g0Wih, g0Wih, g0Whh,
                                               g0bih, g0bhh, states);
  }
  readout_kernel<<<(NN + 3) / 4, 256, 0, stream>>>(states, n2e, r1w, r1b, out, 0);

  for (int s = 0; s < 3; ++s) {
    hipMemsetAsync(agg, 0, (size_t)NN * HH * sizeof(float), stream);
    msg_kernel<<<mgrid, 256, 0, stream>>>(states, esrc, etgt, msgW, msgb, agg, 1);
    gru_kernel<1><<<NN / MT, 384, 0, stream>>>(initb, agg, g1Wih, g1Wih + HH * 384, g1Whh,
                                               g1bih, g1bhh, states);
  }
  readout_kernel<<<(NN + 3) / 4, 256, 0, stream>>>(states, n2e, r2w, r2b, out, HH);
}

// Round 2
// 2237.381 us; speedup vs baseline: 2.3710x; 2.3710x over previous
//
#include <hip/hip_runtime.h>
#include <hip/hip_bf16.h>

#define NN 50000
#define NE 30000
#define NT 8
#define HH 128
#define NB 64
#define CONT 96
#define MT 16
#define TPB 16   // 16-edge tiles per block in msg kernel

typedef __attribute__((ext_vector_type(8))) short short8;
typedef __attribute__((ext_vector_type(4))) float f32x4;

// ---------------------------------------------------------------- init
__global__ __launch_bounds__(256) void init_kernel(
    const int* __restrict__ cid, const int* __restrict__ tg,
    const float* __restrict__ ctab, const float* __restrict__ ttab,
    float* __restrict__ initb, float* __restrict__ states,
    __hip_bfloat16* __restrict__ sbf)
{
  int i = blockIdx.x * 256 + threadIdx.x;
  if (i >= NN * HH) return;
  int n = i >> 7, d = i & 127;
  float v;
  if (d < CONT) v = ctab[(size_t)cid[n] * CONT + d];
  else          v = ttab[(size_t)tg[n] * 32 + (d - CONT)];
  initb[i]  = v;
  states[i] = v;
  sbf[i]    = __float2bfloat16(v);
}

// ---------------------------------------------------------------- W swizzle
// wswz[lt][nt][kk][lane][j] = bf16(W[lt][k = kk*32 + (lane>>4)*8 + j][n = nt*16 + (lane&15)])
// B-fragment slot order identical to the A-fragment slot order used in msg_mfma_kernel,
// so the contraction is invariant to the HW's internal k-slot permutation.
__global__ __launch_bounds__(256) void wswz_kernel(
    const float* __restrict__ msgW, __hip_bfloat16* __restrict__ wswz)
{
  int i = blockIdx.x * 256 + threadIdx.x;   // 262144 total
  int j = i & 7, lane = (i >> 3) & 63, kk = (i >> 9) & 3, nt = (i >> 11) & 7, lt = i >> 14;
  int hi = lane >> 4, lo = lane & 15;
  int k = kk * 32 + hi * 8 + j;
  int n = nt * 16 + lo;
  wswz[i] = __float2bfloat16(msgW[((size_t)lt * HH + k) * HH + n]);
}

// ---------------------------------------------------------------- messages (MFMA)
// grid = (118, 8). Block: 4 waves, each wave owns 16-edge tiles (stride 4).
// Per tile: gather A (16 src rows, bf16), 32 MFMAs vs LDS-staged W[t], scatter-atomicAdd.
__global__ __launch_bounds__(256) void msg_mfma_kernel(
    const __hip_bfloat16* __restrict__ sbf, const int* __restrict__ esrc,
    const int* __restrict__ etgt, const __hip_bfloat16* __restrict__ wswz,
    const float* __restrict__ ball, float* __restrict__ agg, int layer)
{
  __shared__ short8 Wl[8 * 4 * 64];  // 32KB: [nt][kk][lane] -> 8 bf16
  const int t = blockIdx.y;
  {
    const float4* wg = (const float4*)(wswz + (size_t)(layer * NT + t) * 16384);
    float4* wl = (float4*)Wl;
    for (int i = threadIdx.x; i < 2048; i += 256) wl[i] = wg[i];
  }
  const int lane = threadIdx.x & 63;
  const int wv   = threadIdx.x >> 6;
  const int hi = lane >> 4, lo = lane & 15;
  float bias_v[8];
#pragma unroll
  for (int nt = 0; nt < 8; ++nt)
    bias_v[nt] = ball[(layer * NT + t) * HH + nt * 16 + lo];
  __syncthreads();

  const int tile_end = min((int)(blockIdx.x + 1) * TPB, NE / 16);
  for (int tile = blockIdx.x * TPB + wv; tile < tile_end; tile += 4) {
    const int e0 = tile * 16;
    const int src = esrc[t * NE + e0 + lo];          // A row m = lo
    const short* srow = (const short*)(sbf + (size_t)src * HH);
    short8 a[4];
#pragma unroll
    for (int kk = 0; kk < 4; ++kk)
      a[kk] = *(const short8*)(srow + kk * 32 + hi * 8);
    int tgt[4];
#pragma unroll
    for (int r = 0; r < 4; ++r) tgt[r] = etgt[t * NE + e0 + hi * 4 + r];
    f32x4 acc[8];
#pragma unroll
    for (int nt = 0; nt < 8; ++nt) acc[nt] = (f32x4){0.f, 0.f, 0.f, 0.f};
#pragma unroll
    for (int nt = 0; nt < 8; ++nt)
#pragma unroll
      for (int kk = 0; kk < 4; ++kk)
        acc[nt] = __builtin_amdgcn_mfma_f32_16x16x32_bf16(
            a[kk], Wl[(nt * 4 + kk) * 64 + lane], acc[nt], 0, 0, 0);
    // D[row = hi*4+r][col = nt*16+lo] -> edge (e0 + hi*4 + r), dim (nt*16+lo)
#pragma unroll
    for (int nt = 0; nt < 8; ++nt)
#pragma unroll
      for (int r = 0; r < 4; ++r)
        atomicAdd(&agg[(size_t)tgt[r] * HH + nt * 16 + lo], acc[nt][r] + bias_v[nt]);
  }
}

// ---------------------------------------------------------------- fused GRU
template <int TWOK>
__global__ __launch_bounds__(384) void gru_kernel(
    const float* __restrict__ xa, const float* __restrict__ xb,
    const float* __restrict__ Wih, const float* __restrict__ Wib,
    const float* __restrict__ Whh,
    const float* __restrict__ bih, const float* __restrict__ bhh,
    float* __restrict__ states, __hip_bfloat16* __restrict__ sbf)
{
  __shared__ float smem[MT * 384 * 2];  // 48KB
  float* xaT = smem;                // [128][MT]
  float* xbT = smem + HH * MT;
  float* hT  = smem + 2 * HH * MT;
  float* gi_s = smem;               // aliases tiles after first phase
  float* gh_s = smem + MT * 384;

  const int nb  = blockIdx.x * MT;
  const int tid = threadIdx.x;

  for (int i = tid; i < HH * MT; i += 384) {
    int m = i >> 7, k = i & 127;
    xaT[k * MT + m] = xa[(size_t)(nb + m) * HH + k];
    hT [k * MT + m] = states[(size_t)(nb + m) * HH + k];
    if (TWOK) xbT[k * MT + m] = xb[(size_t)(nb + m) * HH + k];
  }
  __syncthreads();

  float acc_i[MT], acc_h[MT];
  const float bi = bih[tid], bh = bhh[tid];
#pragma unroll
  for (int m = 0; m < MT; ++m) { acc_i[m] = bi; acc_h[m] = bh; }

  for (int k = 0; k < HH; ++k) {
    const float wa = Wih[k * 384 + tid];
    const float wh = Whh[k * 384 + tid];
    float wb = 0.f;
    if (TWOK) wb = Wib[k * 384 + tid];
#pragma unroll
    for (int m = 0; m < MT; ++m) {
      acc_i[m] += xaT[k * MT + m] * wa;
      acc_h[m] += hT [k * MT + m] * wh;
      if (TWOK) acc_i[m] += xbT[k * MT + m] * wb;
    }
  }
  __syncthreads();
#pragma unroll
  for (int m = 0; m < MT; ++m) {
    gi_s[m * 384 + tid] = acc_i[m];
    gh_s[m * 384 + tid] = acc_h[m];
  }
  __syncthreads();

  if (tid < HH) {
    for (int m = 0; m < MT; ++m) {
      const float ir  = gi_s[m * 384 + tid];
      const float iz  = gi_s[m * 384 + tid + 128];
      const float inn = gi_s[m * 384 + tid + 256];
      const float hr  = gh_s[m * 384 + tid];
      const float hz  = gh_s[m * 384 + tid + 128];
      const float hn  = gh_s[m * 384 + tid + 256];
      const float r = 1.f / (1.f + __expf(-(ir + hr)));
      const float z = 1.f / (1.f + __expf(-(iz + hz)));
      const float nn = tanhf(inn + r * hn);
      const float hcur = states[(size_t)(nb + m) * HH + tid];
      const float hnew = (1.f - z) * nn + z * hcur;
      states[(size_t)(nb + m) * HH + tid] = hnew;
      sbf[(size_t)(nb + m) * HH + tid] = __float2bfloat16(hnew);
    }
  }
}

// ---------------------------------------------------------------- readout
__global__ __launch_bounds__(256) void readout_kernel(
    const float* __restrict__ states, const int* __restrict__ n2e,
    const float* __restrict__ rw, const float* __restrict__ rb,
    float* __restrict__ out, int coff)
{
  const int lane = threadIdx.x & 63;
  const int n = blockIdx.x * 4 + (threadIdx.x >> 6);
  if (n >= NN) return;
  const float s0 = states[(size_t)n * HH + lane];
  const float s1 = states[(size_t)n * HH + lane + 64];
  float p = s0 * rw[lane] + s1 * rw[lane + 64];
#pragma unroll
  for (int o = 32; o; o >>= 1) p += __shfl_xor(p, o, 64);
  const float g = 1.f / (1.f + __expf(-(p + rb[0])));
  const int ex = n2e[n];
  atomicAdd(&out[(size_t)ex * (2 * HH) + coff + lane], g * s0);
  atomicAdd(&out[(size_t)ex * (2 * HH) + coff + lane + 64], g * s1);
}

// ---------------------------------------------------------------- launch
extern "C" void kernel_launch(void* const* d_in, const int* in_sizes, int n_in,
                              void* d_out, int out_size, void* d_ws, size_t ws_size,
                              hipStream_t stream)
{
  const int*   cid   = (const int*)d_in[0];
  const int*   tg    = (const int*)d_in[1];
  const int*   esrc  = (const int*)d_in[2];
  const int*   etgt  = (const int*)d_in[3];
  const int*   n2e   = (const int*)d_in[4];
  const float* ctab  = (const float*)d_in[5];
  const float* ttab  = (const float*)d_in[6];
  const float* msgW  = (const float*)d_in[7];
  const float* msgb  = (const float*)d_in[8];
  const float* g0Wih = (const float*)d_in[9];
  const float* g0Whh = (const float*)d_in[10];
  const float* g0bih = (const float*)d_in[11];
  const float* g0bhh = (const float*)d_in[12];
  const float* g1Wih = (const float*)d_in[13];
  const float* g1Whh = (const float*)d_in[14];
  const float* g1bih = (const float*)d_in[15];
  const float* g1bhh = (const float*)d_in[16];
  const float* r1w   = (const float*)d_in[17];
  const float* r1b   = (const float*)d_in[18];
  const float* r2w   = (const float*)d_in[19];
  const float* r2b   = (const float*)d_in[20];

  float* out    = (float*)d_out;
  float* states = (float*)d_ws;
  float* initb  = states + (size_t)NN * HH;
  float* agg    = initb  + (size_t)NN * HH;
  __hip_bfloat16* sbf  = (__hip_bfloat16*)(agg + (size_t)NN * HH);
  __hip_bfloat16* wswz = sbf + (size_t)NN * HH;

  hipMemsetAsync(d_out, 0, (size_t)NB * 2 * HH * sizeof(float), stream);
  wswz_kernel<<<262144 / 256, 256, 0, stream>>>(msgW, wswz);
  init_kernel<<<(NN * HH + 255) / 256, 256, 0, stream>>>(cid, tg, ctab, ttab, initb, states, sbf);

  dim3 mgrid((NE / 16 + TPB - 1) / TPB, NT);
  for (int s = 0; s < 3; ++s) {
    hipMemsetAsync(agg, 0, (size_t)NN * HH * sizeof(float), stream);
    msg_mfma_kernel<<<mgrid, 256, 0, stream>>>(sbf, esrc, etgt, wswz, msgb, agg, 0);
    gru_kernel<0><<<NN / MT, 384, 0, stream>>>(agg, nullptr, g0Wih, g0Wih, g0Whh,
                                               g0bih, g0bhh, states, sbf);
  }
  readout_kernel<<<(NN + 3) / 4, 256, 0, stream>>>(states, n2e, r1w, r1b, out, 0);

  for (int s = 0; s < 3; ++s) {
    hipMemsetAsync(agg, 0, (size_t)NN * HH * sizeof(float), stream);
    msg_mfma_kernel<<<mgrid, 256, 0, stream>>>(sbf, esrc, etgt, wswz, msgb, agg, 1);
    gru_kernel<1><<<NN / MT, 384, 0, stream>>>(initb, agg, g1Wih, g1Wih + HH * 384, g1Whh,
                                               g1bih, g1bhh, states, sbf);
  }
  readout_kernel<<<(NN + 3) / 4, 256, 0, stream>>>(states, n2e, r2w, r2b, out, HH);
}

// Round 3
// 1132.115 us; speedup vs baseline: 4.6859x; 1.9763x over previous
//
#include <hip/hip_runtime.h>
#include <hip/hip_bf16.h>

#define NN 50000
#define NE 30000
#define NT 8
#define HH 128
#define NB 64
#define CONT 96
#define TPB 16   // 16-edge tiles per block in msg kernel

typedef __attribute__((ext_vector_type(8))) short short8;
typedef __attribute__((ext_vector_type(4))) float f32x4;

__device__ __forceinline__ float sigm(float x) { return 1.f / (1.f + __expf(-x)); }

// ---------------------------------------------------------------- init
__global__ __launch_bounds__(256) void init_kernel(
    const int* __restrict__ cid, const int* __restrict__ tg,
    const float* __restrict__ ctab, const float* __restrict__ ttab,
    float* __restrict__ initb, float* __restrict__ states,
    __hip_bfloat16* __restrict__ sbf, __hip_bfloat16* __restrict__ ibf)
{
  int i = blockIdx.x * 256 + threadIdx.x;
  if (i >= NN * HH) return;
  int n = i >> 7, d = i & 127;
  float v;
  if (d < CONT) v = ctab[(size_t)cid[n] * CONT + d];
  else          v = ttab[(size_t)tg[n] * 32 + (d - CONT)];
  initb[i]  = v;
  states[i] = v;
  sbf[i]    = __float2bfloat16(v);
  ibf[i]    = __float2bfloat16(v);
}

// ---------------------------------------------------------------- msg W swizzle
// wswz[lt][nt][kk][lane][j] = bf16(W[lt][k = kk*32 + (lane>>4)*8 + j][n = nt*16 + (lane&15)])
__global__ __launch_bounds__(256) void wswz_kernel(
    const float* __restrict__ msgW, __hip_bfloat16* __restrict__ wswz)
{
  int i = blockIdx.x * 256 + threadIdx.x;   // 262144 total
  int j = i & 7, lane = (i >> 3) & 63, kk = (i >> 9) & 3, nt = (i >> 11) & 7, lt = i >> 14;
  int hi = lane >> 4, lo = lane & 15;
  int k = kk * 32 + hi * 8 + j;
  int n = nt * 16 + lo;
  wswz[i] = __float2bfloat16(msgW[((size_t)lt * HH + k) * HH + n]);
}

// ---------------------------------------------------------------- GRU W swizzle
// out[nt][kk][lane][j] = bf16(W[k = kk*32 + hi*8 + j][n = nt*16 + lo]), W is [K][384]
__global__ __launch_bounds__(256) void gru_wswz_kernel(
    const float* __restrict__ W, __hip_bfloat16* __restrict__ out, int KSL)
{
  int total = 24 * KSL * 512;
  int i = blockIdx.x * 256 + threadIdx.x;
  if (i >= total) return;
  int j = i & 7, lane = (i >> 3) & 63, kk = (i >> 9) % KSL, nt = i / (KSL * 512);
  int hi = lane >> 4, lo = lane & 15;
  int k = kk * 32 + hi * 8 + j;
  int n = nt * 16 + lo;
  out[i] = __float2bfloat16(W[(size_t)k * 384 + n]);
}

// ---------------------------------------------------------------- messages (MFMA)
__global__ __launch_bounds__(256) void msg_mfma_kernel(
    const __hip_bfloat16* __restrict__ sbf, const int* __restrict__ esrc,
    const int* __restrict__ etgt, const __hip_bfloat16* __restrict__ wswz,
    const float* __restrict__ ball, float* __restrict__ agg, int layer)
{
  __shared__ short8 Wl[8 * 4 * 64];  // 32KB
  const int t = blockIdx.y;
  {
    const float4* wg = (const float4*)(wswz + (size_t)(layer * NT + t) * 16384);
    float4* wl = (float4*)Wl;
    for (int i = threadIdx.x; i < 2048; i += 256) wl[i] = wg[i];
  }
  const int lane = threadIdx.x & 63;
  const int wv   = threadIdx.x >> 6;
  const int hi = lane >> 4, lo = lane & 15;
  float bias_v[8];
#pragma unroll
  for (int nt = 0; nt < 8; ++nt)
    bias_v[nt] = ball[(layer * NT + t) * HH + nt * 16 + lo];
  __syncthreads();

  const int tile_end = min((int)(blockIdx.x + 1) * TPB, NE / 16);
  for (int tile = blockIdx.x * TPB + wv; tile < tile_end; tile += 4) {
    const int e0 = tile * 16;
    const int src = esrc[t * NE + e0 + lo];
    const short* srow = (const short*)(sbf + (size_t)src * HH);
    short8 a[4];
#pragma unroll
    for (int kk = 0; kk < 4; ++kk)
      a[kk] = *(const short8*)(srow + kk * 32 + hi * 8);
    int tgt[4];
#pragma unroll
    for (int r = 0; r < 4; ++r) tgt[r] = etgt[t * NE + e0 + hi * 4 + r];
    f32x4 acc[8];
#pragma unroll
    for (int nt = 0; nt < 8; ++nt) acc[nt] = (f32x4){0.f, 0.f, 0.f, 0.f};
#pragma unroll
    for (int nt = 0; nt < 8; ++nt)
#pragma unroll
      for (int kk = 0; kk < 4; ++kk)
        acc[nt] = __builtin_amdgcn_mfma_f32_16x16x32_bf16(
            a[kk], Wl[(nt * 4 + kk) * 64 + lane], acc[nt], 0, 0, 0);
#pragma unroll
    for (int nt = 0; nt < 8; ++nt)
#pragma unroll
      for (int r = 0; r < 4; ++r)
        atomicAdd(&agg[(size_t)tgt[r] * HH + nt * 16 + lo], acc[nt][r] + bias_v[nt]);
  }
}

// ---------------------------------------------------------------- GRU (MFMA)
// One wave per 16-node tile, no LDS. Gate-grouped dt-loop: 6 accumulators
// (gi/gh x r/z/n for one 16-col slice); gate math fully in-register.
template <int KSL>  // x k-slices: 4 (layer0) or 8 (layer1, concat(init,agg))
__global__ __launch_bounds__(256) void gru_mfma_kernel(
    const float* __restrict__ xa,               // agg fp32 [NN][128]
    const __hip_bfloat16* __restrict__ ibf,     // init bf16 (layer1)
    const __hip_bfloat16* __restrict__ hbf,     // states bf16
    const __hip_bfloat16* __restrict__ Wih_s,   // [24][KSL][64][8]
    const __hip_bfloat16* __restrict__ Whh_s,   // [24][4][64][8]
    const float* __restrict__ bih, const float* __restrict__ bhh,
    float* __restrict__ states, __hip_bfloat16* __restrict__ sbf_out)
{
  const int lane = threadIdx.x & 63;
  const int wv   = threadIdx.x >> 6;
  const int tile = blockIdx.x * 4 + wv;
  if (tile >= NN / 16) return;
  const int nb = tile * 16;
  const int hi = lane >> 4, lo = lane & 15;

  // A fragments: x
  short8 ax[KSL];
  if (KSL == 8) {
    const short* irow = (const short*)(ibf + (size_t)(nb + lo) * HH);
#pragma unroll
    for (int kk = 0; kk < 4; ++kk)
      ax[kk] = *(const short8*)(irow + kk * 32 + hi * 8);
    const float* xrow = xa + (size_t)(nb + lo) * HH;
#pragma unroll
    for (int kk = 4; kk < KSL; ++kk) {
      const float* p = xrow + (kk - 4) * 32 + hi * 8;
      short8 v;
#pragma unroll
      for (int j = 0; j < 8; ++j)
        ((__hip_bfloat16*)&v)[j] = __float2bfloat16(p[j]);
      ax[kk] = v;
    }
  } else {
    const float* xrow = xa + (size_t)(nb + lo) * HH;
#pragma unroll
    for (int kk = 0; kk < KSL; ++kk) {
      const float* p = xrow + kk * 32 + hi * 8;
      short8 v;
#pragma unroll
      for (int j = 0; j < 8; ++j)
        ((__hip_bfloat16*)&v)[j] = __float2bfloat16(p[j]);
      ax[kk] = v;
    }
  }
  // A fragments: h
  short8 ah[4];
  {
    const short* hrow = (const short*)(hbf + (size_t)(nb + lo) * HH);
#pragma unroll
    for (int kk = 0; kk < 4; ++kk)
      ah[kk] = *(const short8*)(hrow + kk * 32 + hi * 8);
  }

  const short8* Bih = (const short8*)Wih_s;
  const short8* Bhh = (const short8*)Whh_s;

#pragma unroll
  for (int dt = 0; dt < 8; ++dt) {
    f32x4 gir = {0,0,0,0}, giz = {0,0,0,0}, gin = {0,0,0,0};
    f32x4 ghr = {0,0,0,0}, ghz = {0,0,0,0}, ghn = {0,0,0,0};
#pragma unroll
    for (int kk = 0; kk < KSL; ++kk) {
      gir = __builtin_amdgcn_mfma_f32_16x16x32_bf16(ax[kk], Bih[((dt     ) * KSL + kk) * 64 + lane], gir, 0, 0, 0);
      giz = __builtin_amdgcn_mfma_f32_16x16x32_bf16(ax[kk], Bih[((dt +  8) * KSL + kk) * 64 + lane], giz, 0, 0, 0);
      gin = __builtin_amdgcn_mfma_f32_16x16x32_bf16(ax[kk], Bih[((dt + 16) * KSL + kk) * 64 + lane], gin, 0, 0, 0);
    }
#pragma unroll
    for (int kk = 0; kk < 4; ++kk) {
      ghr = __builtin_amdgcn_mfma_f32_16x16x32_bf16(ah[kk], Bhh[((dt     ) * 4 + kk) * 64 + lane], ghr, 0, 0, 0);
      ghz = __builtin_amdgcn_mfma_f32_16x16x32_bf16(ah[kk], Bhh[((dt +  8) * 4 + kk) * 64 + lane], ghz, 0, 0, 0);
      ghn = __builtin_amdgcn_mfma_f32_16x16x32_bf16(ah[kk], Bhh[((dt + 16) * 4 + kk) * 64 + lane], ghn, 0, 0, 0);
    }
    const int c = dt * 16 + lo;
    const float bir = bih[c], biz = bih[c + 128], bin = bih[c + 256];
    const float bhr = bhh[c], bhz = bhh[c + 128], bhn = bhh[c + 256];
#pragma unroll
    for (int r = 0; r < 4; ++r) {
      const int node = nb + hi * 4 + r;
      const float rg = sigm(gir[r] + bir + ghr[r] + bhr);
      const float zg = sigm(giz[r] + biz + ghz[r] + bhz);
      const float ng = tanhf(gin[r] + bin + rg * (ghn[r] + bhn));
      const float hcur = states[(size_t)node * HH + c];
      const float hnew = (1.f - zg) * ng + zg * hcur;
      states[(size_t)node * HH + c] = hnew;
      sbf_out[(size_t)node * HH + c] = __float2bfloat16(hnew);
    }
  }
}

// ---------------------------------------------------------------- readout
__global__ __launch_bounds__(256) void readout_kernel(
    const float* __restrict__ states, const int* __restrict__ n2e,
    const float* __restrict__ rw, const float* __restrict__ rb,
    float* __restrict__ out, int coff)
{
  const int lane = threadIdx.x & 63;
  const int n = blockIdx.x * 4 + (threadIdx.x >> 6);
  if (n >= NN) return;
  const float s0 = states[(size_t)n * HH + lane];
  const float s1 = states[(size_t)n * HH + lane + 64];
  float p = s0 * rw[lane] + s1 * rw[lane + 64];
#pragma unroll
  for (int o = 32; o; o >>= 1) p += __shfl_xor(p, o, 64);
  const float g = 1.f / (1.f + __expf(-(p + rb[0])));
  const int ex = n2e[n];
  atomicAdd(&out[(size_t)ex * (2 * HH) + coff + lane], g * s0);
  atomicAdd(&out[(size_t)ex * (2 * HH) + coff + lane + 64], g * s1);
}

// ---------------------------------------------------------------- launch
extern "C" void kernel_launch(void* const* d_in, const int* in_sizes, int n_in,
                              void* d_out, int out_size, void* d_ws, size_t ws_size,
                              hipStream_t stream)
{
  const int*   cid   = (const int*)d_in[0];
  const int*   tg    = (const int*)d_in[1];
  const int*   esrc  = (const int*)d_in[2];
  const int*   etgt  = (const int*)d_in[3];
  const int*   n2e   = (const int*)d_in[4];
  const float* ctab  = (const float*)d_in[5];
  const float* ttab  = (const float*)d_in[6];
  const float* msgW  = (const float*)d_in[7];
  const float* msgb  = (const float*)d_in[8];
  const float* g0Wih = (const float*)d_in[9];
  const float* g0Whh = (const float*)d_in[10];
  const float* g0bih = (const float*)d_in[11];
  const float* g0bhh = (const float*)d_in[12];
  const float* g1Wih = (const float*)d_in[13];
  const float* g1Whh = (const float*)d_in[14];
  const float* g1bih = (const float*)d_in[15];
  const float* g1bhh = (const float*)d_in[16];
  const float* r1w   = (const float*)d_in[17];
  const float* r1b   = (const float*)d_in[18];
  const float* r2w   = (const float*)d_in[19];
  const float* r2b   = (const float*)d_in[20];

  float* out    = (float*)d_out;
  float* states = (float*)d_ws;
  float* initb  = states + (size_t)NN * HH;
  float* agg    = initb  + (size_t)NN * HH;
  __hip_bfloat16* sbf  = (__hip_bfloat16*)(agg + (size_t)NN * HH);
  __hip_bfloat16* ibf  = sbf + (size_t)NN * HH;
  __hip_bfloat16* wswz = ibf + (size_t)NN * HH;
  __hip_bfloat16* w0ih = wswz + 262144;           // 24*4*512
  __hip_bfloat16* w0hh = w0ih + 24 * 4 * 512;
  __hip_bfloat16* w1ih = w0hh + 24 * 4 * 512;     // 24*8*512
  __hip_bfloat16* w1hh = w1ih + 24 * 8 * 512;

  hipMemsetAsync(d_out, 0, (size_t)NB * 2 * HH * sizeof(float), stream);
  wswz_kernel<<<262144 / 256, 256, 0, stream>>>(msgW, wswz);
  gru_wswz_kernel<<<(24 * 4 * 512 + 255) / 256, 256, 0, stream>>>(g0Wih, w0ih, 4);
  gru_wswz_kernel<<<(24 * 4 * 512 + 255) / 256, 256, 0, stream>>>(g0Whh, w0hh, 4);
  gru_wswz_kernel<<<(24 * 8 * 512 + 255) / 256, 256, 0, stream>>>(g1Wih, w1ih, 8);
  gru_wswz_kernel<<<(24 * 4 * 512 + 255) / 256, 256, 0, stream>>>(g1Whh, w1hh, 4);
  init_kernel<<<(NN * HH + 255) / 256, 256, 0, stream>>>(cid, tg, ctab, ttab, initb, states, sbf, ibf);

  dim3 mgrid((NE / 16 + TPB - 1) / TPB, NT);
  const int gblocks = (NN / 16 + 3) / 4;
  for (int s = 0; s < 3; ++s) {
    hipMemsetAsync(agg, 0, (size_t)NN * HH * sizeof(float), stream);
    msg_mfma_kernel<<<mgrid, 256, 0, stream>>>(sbf, esrc, etgt, wswz, msgb, agg, 0);
    gru_mfma_kernel<4><<<gblocks, 256, 0, stream>>>(agg, ibf, sbf, w0ih, w0hh,
                                                    g0bih, g0bhh, states, sbf);
  }
  readout_kernel<<<(NN + 3) / 4, 256, 0, stream>>>(states, n2e, r1w, r1b, out, 0);

  for (int s = 0; s < 3; ++s) {
    hipMemsetAsync(agg, 0, (size_t)NN * HH * sizeof(float), stream);
    msg_mfma_kernel<<<mgrid, 256, 0, stream>>>(sbf, esrc, etgt, wswz, msgb, agg, 1);
    gru_mfma_kernel<8><<<gblocks, 256, 0, stream>>>(agg, ibf, sbf, w1ih, w1hh,
                                                    g1bih, g1bhh, states, sbf);
  }
  readout_kernel<<<(NN + 3) / 4, 256, 0, stream>>>(states, n2e, r2w, r2b, out, HH);
}

// Round 4
// 1001.964 us; speedup vs baseline: 5.2945x; 1.1299x over previous
//
#include <hip/hip_runtime.h>
#include <hip/hip_bf16.h>

#define NN 50000
#define NE 30000
#define NT 8
#define HH 128
#define NB 64
#define CONT 96
#define TPB 16
#define EDGES (NT * NE)

typedef __attribute__((ext_vector_type(8))) short short8;
typedef __attribute__((ext_vector_type(4))) float f32x4;

__device__ __forceinline__ float sigm(float x) { return 1.f / (1.f + __expf(-x)); }
__device__ __forceinline__ unsigned short bfbits(float x) {
  __hip_bfloat16 b = __float2bfloat16(x);
  return *(unsigned short*)&b;
}

// ---------------------------------------------------------------- init
__global__ __launch_bounds__(256) void init_kernel(
    const int* __restrict__ cid, const int* __restrict__ tg,
    const float* __restrict__ ctab, const float* __restrict__ ttab,
    float* __restrict__ states,
    __hip_bfloat16* __restrict__ sbf, __hip_bfloat16* __restrict__ ibf)
{
  int i = blockIdx.x * 256 + threadIdx.x;
  if (i >= NN * HH) return;
  int n = i >> 7, d = i & 127;
  float v;
  if (d < CONT) v = ctab[(size_t)cid[n] * CONT + d];
  else          v = ttab[(size_t)tg[n] * 32 + (d - CONT)];
  states[i] = v;
  sbf[i]    = __float2bfloat16(v);
  ibf[i]    = __float2bfloat16(v);
}

// ---------------------------------------------------------------- CSR build
__global__ __launch_bounds__(256) void hist_kernel(
    const int* __restrict__ etgt, int* __restrict__ cnt)
{
  int i = blockIdx.x * 256 + threadIdx.x;
  if (i >= EDGES) return;
  atomicAdd(&cnt[etgt[i]], 1);
}

__global__ __launch_bounds__(1024) void scan_kernel(
    const int* __restrict__ cnt, int* __restrict__ row_ptr, int* __restrict__ cnt2)
{
  __shared__ int part[1024];
  const int tid = threadIdx.x;
  const int CH = (NN + 1023) / 1024;  // 49
  const int base = tid * CH;
  int s = 0;
  for (int k = 0; k < CH; ++k) { int idx = base + k; if (idx < NN) s += cnt[idx]; }
  part[tid] = s;
  __syncthreads();
  for (int off = 1; off < 1024; off <<= 1) {
    int v = (tid >= off) ? part[tid - off] : 0;
    __syncthreads();
    part[tid] += v;
    __syncthreads();
  }
  int run = (tid ? part[tid - 1] : 0);
  for (int k = 0; k < CH; ++k) {
    int idx = base + k;
    if (idx < NN) { row_ptr[idx] = run; cnt2[idx] = run; run += cnt[idx]; }
  }
  if (tid == 1023) row_ptr[NN] = run;
}

__global__ __launch_bounds__(256) void scatter_kernel(
    const int* __restrict__ etgt, int* __restrict__ cnt2, int* __restrict__ perm)
{
  int i = blockIdx.x * 256 + threadIdx.x;
  if (i >= EDGES) return;
  perm[i] = atomicAdd(&cnt2[etgt[i]], 1);
}

// ---------------------------------------------------------------- msg W swizzle
// B slot (kk,lane,j) <-> k = kk*32 + hi*8 + j (matches A gather from row-major sbf)
__global__ __launch_bounds__(256) void wswz_kernel(
    const float* __restrict__ msgW, __hip_bfloat16* __restrict__ wswz)
{
  int i = blockIdx.x * 256 + threadIdx.x;   // 262144 total
  int j = i & 7, lane = (i >> 3) & 63, kk = (i >> 9) & 3, nt = (i >> 11) & 7, lt = i >> 14;
  int hi = lane >> 4, lo = lane & 15;
  int k = kk * 32 + hi * 8 + j;
  int n = nt * 16 + lo;
  wswz[i] = __float2bfloat16(msgW[((size_t)lt * HH + k) * HH + n]);
}

// ---------------------------------------------------------------- GRU W swizzle
// mode 0: k = p (row-major operand). mode 1: k = sigma^-1(p) (agg sigma-order).
// mode 2: K=256, first 128 identity (init), second 128 sigma (agg).
__global__ __launch_bounds__(256) void gru_wswz_kernel(
    const float* __restrict__ W, __hip_bfloat16* __restrict__ out, int KSL, int mode)
{
  int total = 24 * KSL * 512;
  int i = blockIdx.x * 256 + threadIdx.x;
  if (i >= total) return;
  int j = i & 7, lane = (i >> 3) & 63, kk = (i >> 9) % KSL, nt = i / (KSL * 512);
  int hi = lane >> 4, lo = lane & 15;
  int p = kk * 32 + hi * 8 + j;
  int k;
  if (mode == 0)      k = p;
  else if (mode == 1) k = (p & 7) * 16 + (p >> 3);
  else                k = (p < 128) ? p : 128 + ((p - 128) & 7) * 16 + ((p - 128) >> 3);
  int n = nt * 16 + lo;
  out[i] = __float2bfloat16(W[(size_t)k * 384 + n]);
}

// ---------------------------------------------------------------- messages (MFMA, no atomics)
// Writes per-edge message rows (bf16, sigma dim order, +bias) to msgs[perm[e]].
__global__ __launch_bounds__(256) void msg_mfma_kernel(
    const __hip_bfloat16* __restrict__ sbf, const int* __restrict__ esrc,
    const int* __restrict__ perm, const __hip_bfloat16* __restrict__ wswz,
    const float* __restrict__ ball, __hip_bfloat16* __restrict__ msgs, int layer)
{
  __shared__ short8 Wl[8 * 4 * 64];  // 32KB
  const int t = blockIdx.y;
  {
    const float4* wg = (const float4*)(wswz + (size_t)(layer * NT + t) * 16384);
    float4* wl = (float4*)Wl;
    for (int i = threadIdx.x; i < 2048; i += 256) wl[i] = wg[i];
  }
  const int lane = threadIdx.x & 63;
  const int wv   = threadIdx.x >> 6;
  const int hi = lane >> 4, lo = lane & 15;
  float bias_v[8];
#pragma unroll
  for (int nt = 0; nt < 8; ++nt)
    bias_v[nt] = ball[(layer * NT + t) * HH + nt * 16 + lo];
  __syncthreads();

  const int tile_end = min((int)(blockIdx.x + 1) * TPB, NE / 16);
  for (int tile = blockIdx.x * TPB + wv; tile < tile_end; tile += 4) {
    const int e0 = tile * 16;
    const int src = esrc[t * NE + e0 + lo];
    const short* srow = (const short*)(sbf + (size_t)src * HH);
    short8 a[4];
#pragma unroll
    for (int kk = 0; kk < 4; ++kk)
      a[kk] = *(const short8*)(srow + kk * 32 + hi * 8);
    int slot[4];
#pragma unroll
    for (int r = 0; r < 4; ++r) slot[r] = perm[t * NE + e0 + hi * 4 + r];
    f32x4 acc[8];
#pragma unroll
    for (int nt = 0; nt < 8; ++nt) acc[nt] = (f32x4){0.f, 0.f, 0.f, 0.f};
#pragma unroll
    for (int nt = 0; nt < 8; ++nt)
#pragma unroll
      for (int kk = 0; kk < 4; ++kk)
        acc[nt] = __builtin_amdgcn_mfma_f32_16x16x32_bf16(
            a[kk], Wl[(nt * 4 + kk) * 64 + lane], acc[nt], 0, 0, 0);
    // D[row=hi*4+r][dim nt*16+lo]; store row at sigma position lo*8+nt => short8/lane
#pragma unroll
    for (int r = 0; r < 4; ++r) {
      short8 m;
#pragma unroll
      for (int nt = 0; nt < 8; ++nt)
        ((unsigned short*)&m)[nt] = bfbits(acc[nt][r] + bias_v[nt]);
      *(short8*)((short*)msgs + (size_t)slot[r] * HH + lo * 8) = m;
    }
  }
}

// ---------------------------------------------------------------- reduce (CSR gather-sum)
// One wave per node: sum contiguous bf16 msg rows in f32, write agg (bf16, sigma order).
__global__ __launch_bounds__(256) void reduce_kernel(
    const __hip_bfloat16* __restrict__ msgs, const int* __restrict__ row_ptr,
    __hip_bfloat16* __restrict__ agg)
{
  const int lane = threadIdx.x & 63;
  const int n = blockIdx.x * 4 + (threadIdx.x >> 6);
  if (n >= NN) return;
  const int b = row_ptr[n], e = row_ptr[n + 1];
  float a0 = 0.f, a1 = 0.f;
  for (int i = b; i < e; ++i) {
    unsigned int v = *(const unsigned int*)((const short*)msgs + (size_t)i * HH + lane * 2);
    a0 += __uint_as_float(v << 16);
    a1 += __uint_as_float(v & 0xffff0000u);
  }
  unsigned int o = ((unsigned int)bfbits(a1) << 16) | bfbits(a0);
  *(unsigned int*)((short*)agg + (size_t)n * HH + lane * 2) = o;
}

// ---------------------------------------------------------------- GRU (MFMA, 2 tiles/wave)
template <int KSL>
__global__ __launch_bounds__(256) void gru_mfma_kernel(
    const __hip_bfloat16* __restrict__ agg,     // sigma order
    const __hip_bfloat16* __restrict__ ibf,     // row-major (layer1)
    const __hip_bfloat16* __restrict__ hbf,     // row-major
    const __hip_bfloat16* __restrict__ Wih_s,
    const __hip_bfloat16* __restrict__ Whh_s,
    const float* __restrict__ bih, const float* __restrict__ bhh,
    float* __restrict__ states, __hip_bfloat16* __restrict__ sbf_out)
{
  const int lane = threadIdx.x & 63;
  const int wv   = threadIdx.x >> 6;
  const int NTILE = NN / 16;          // 3125
  const int t0 = (blockIdx.x * 4 + wv) * 2;
  if (t0 >= NTILE) return;
  const bool two = (t0 + 1 < NTILE);
  const int hi = lane >> 4, lo = lane & 15;

  short8 ax[2][KSL], ah[2][4];
#pragma unroll
  for (int u = 0; u < 2; ++u) {
    const int nb = (u == 0 || two) ? (t0 + u) * 16 : t0 * 16;
    const short* arow = (const short*)(agg + (size_t)(nb + lo) * HH);
    const short* hrow = (const short*)(hbf + (size_t)(nb + lo) * HH);
    if (KSL == 8) {
      const short* irow = (const short*)(ibf + (size_t)(nb + lo) * HH);
#pragma unroll
      for (int kk = 0; kk < 4; ++kk) {
        ax[u][kk]     = *(const short8*)(irow + kk * 32 + hi * 8);
        ax[u][kk + 4] = *(const short8*)(arow + kk * 32 + hi * 8);
      }
    } else {
#pragma unroll
      for (int kk = 0; kk < 4; ++kk)
        ax[u][kk] = *(const short8*)(arow + kk * 32 + hi * 8);
    }
#pragma unroll
    for (int kk = 0; kk < 4; ++kk)
      ah[u][kk] = *(const short8*)(hrow + kk * 32 + hi * 8);
  }

  const short8* Bih = (const short8*)Wih_s;
  const short8* Bhh = (const short8*)Whh_s;

#pragma unroll
  for (int dt = 0; dt < 8; ++dt) {
    f32x4 gi[2][3], gh[2][3];
#pragma unroll
    for (int u = 0; u < 2; ++u)
#pragma unroll
      for (int g = 0; g < 3; ++g) {
        gi[u][g] = (f32x4){0.f, 0.f, 0.f, 0.f};
        gh[u][g] = (f32x4){0.f, 0.f, 0.f, 0.f};
      }
#pragma unroll
    for (int kk = 0; kk < KSL; ++kk)
#pragma unroll
      for (int g = 0; g < 3; ++g) {
        short8 b = Bih[((size_t)(dt + 8 * g) * KSL + kk) * 64 + lane];
        gi[0][g] = __builtin_amdgcn_mfma_f32_16x16x32_bf16(ax[0][kk], b, gi[0][g], 0, 0, 0);
        gi[1][g] = __builtin_amdgcn_mfma_f32_16x16x32_bf16(ax[1][kk], b, gi[1][g], 0, 0, 0);
      }
#pragma unroll
    for (int kk = 0; kk < 4; ++kk)
#pragma unroll
      for (int g = 0; g < 3; ++g) {
        short8 b = Bhh[((size_t)(dt + 8 * g) * 4 + kk) * 64 + lane];
        gh[0][g] = __builtin_amdgcn_mfma_f32_16x16x32_bf16(ah[0][kk], b, gh[0][g], 0, 0, 0);
        gh[1][g] = __builtin_amdgcn_mfma_f32_16x16x32_bf16(ah[1][kk], b, gh[1][g], 0, 0, 0);
      }
    const int c = dt * 16 + lo;
    const float bir = bih[c], biz = bih[c + 128], bin = bih[c + 256];
    const float bhr = bhh[c], bhz = bhh[c + 128], bhn = bhh[c + 256];
    const int uend = two ? 2 : 1;
    for (int u = 0; u < uend; ++u) {
      const int nb = (t0 + u) * 16;
#pragma unroll
      for (int r = 0; r < 4; ++r) {
        const int node = nb + hi * 4 + r;
        const float rg = sigm(gi[u][0][r] + bir + gh[u][0][r] + bhr);
        const float zg = sigm(gi[u][1][r] + biz + gh[u][1][r] + bhz);
        const float ng = tanhf(gi[u][2][r] + bin + rg * (gh[u][2][r] + bhn));
        const float hc = states[(size_t)node * HH + c];
        const float hn2 = (1.f - zg) * ng + zg * hc;
        states[(size_t)node * HH + c] = hn2;
        sbf_out[(size_t)node * HH + c] = __float2bfloat16(hn2);
      }
    }
  }
}

// ---------------------------------------------------------------- readout
__global__ __launch_bounds__(256) void readout_kernel(
    const float* __restrict__ states, const int* __restrict__ n2e,
    const float* __restrict__ rw, const float* __restrict__ rb,
    float* __restrict__ out, int coff)
{
  const int lane = threadIdx.x & 63;
  const int n = blockIdx.x * 4 + (threadIdx.x >> 6);
  if (n >= NN) return;
  const float s0 = states[(size_t)n * HH + lane];
  const float s1 = states[(size_t)n * HH + lane + 64];
  float p = s0 * rw[lane] + s1 * rw[lane + 64];
#pragma unroll
  for (int o = 32; o; o >>= 1) p += __shfl_xor(p, o, 64);
  const float g = 1.f / (1.f + __expf(-(p + rb[0])));
  const int ex = n2e[n];
  atomicAdd(&out[(size_t)ex * (2 * HH) + coff + lane], g * s0);
  atomicAdd(&out[(size_t)ex * (2 * HH) + coff + lane + 64], g * s1);
}

// ---------------------------------------------------------------- launch
extern "C" void kernel_launch(void* const* d_in, const int* in_sizes, int n_in,
                              void* d_out, int out_size, void* d_ws, size_t ws_size,
                              hipStream_t stream)
{
  const int*   cid   = (const int*)d_in[0];
  const int*   tg    = (const int*)d_in[1];
  const int*   esrc  = (const int*)d_in[2];
  const int*   etgt  = (const int*)d_in[3];
  const int*   n2e   = (const int*)d_in[4];
  const float* ctab  = (const float*)d_in[5];
  const float* ttab  = (const float*)d_in[6];
  const float* msgW  = (const float*)d_in[7];
  const float* msgb  = (const float*)d_in[8];
  const float* g0Wih = (const float*)d_in[9];
  const float* g0Whh = (const float*)d_in[10];
  const float* g0bih = (const float*)d_in[11];
  const float* g0bhh = (const float*)d_in[12];
  const float* g1Wih = (const float*)d_in[13];
  const float* g1Whh = (const float*)d_in[14];
  const float* g1bih = (const float*)d_in[15];
  const float* g1bhh = (const float*)d_in[16];
  const float* r1w   = (const float*)d_in[17];
  const float* r1b   = (const float*)d_in[18];
  const float* r2w   = (const float*)d_in[19];
  const float* r2b   = (const float*)d_in[20];

  float* out    = (float*)d_out;
  float* states = (float*)d_ws;
  __hip_bfloat16* sbf  = (__hip_bfloat16*)(states + (size_t)NN * HH);
  __hip_bfloat16* ibf  = sbf + (size_t)NN * HH;
  __hip_bfloat16* agg  = ibf + (size_t)NN * HH;
  __hip_bfloat16* msgs = agg + (size_t)NN * HH;
  __hip_bfloat16* wswz = msgs + (size_t)EDGES * HH;
  __hip_bfloat16* w0ih = wswz + 262144;
  __hip_bfloat16* w0hh = w0ih + 24 * 4 * 512;
  __hip_bfloat16* w1ih = w0hh + 24 * 4 * 512;
  __hip_bfloat16* w1hh = w1ih + 24 * 8 * 512;
  int* row_ptr = (int*)(w1hh + 24 * 4 * 512);
  int* cnt     = row_ptr + NN + 1;
  int* cnt2    = cnt + NN;
  int* perm    = cnt2 + NN;

  hipMemsetAsync(d_out, 0, (size_t)NB * 2 * HH * sizeof(float), stream);
  hipMemsetAsync(cnt, 0, (size_t)NN * sizeof(int), stream);
  const int eblocks = (EDGES + 255) / 256;
  hist_kernel<<<eblocks, 256, 0, stream>>>(etgt, cnt);
  scan_kernel<<<1, 1024, 0, stream>>>(cnt, row_ptr, cnt2);
  scatter_kernel<<<eblocks, 256, 0, stream>>>(etgt, cnt2, perm);

  wswz_kernel<<<262144 / 256, 256, 0, stream>>>(msgW, wswz);
  gru_wswz_kernel<<<(24 * 4 * 512 + 255) / 256, 256, 0, stream>>>(g0Wih, w0ih, 4, 1);
  gru_wswz_kernel<<<(24 * 4 * 512 + 255) / 256, 256, 0, stream>>>(g0Whh, w0hh, 4, 0);
  gru_wswz_kernel<<<(24 * 8 * 512 + 255) / 256, 256, 0, stream>>>(g1Wih, w1ih, 8, 2);
  gru_wswz_kernel<<<(24 * 4 * 512 + 255) / 256, 256, 0, stream>>>(g1Whh, w1hh, 4, 0);
  init_kernel<<<(NN * HH + 255) / 256, 256, 0, stream>>>(cid, tg, ctab, ttab, states, sbf, ibf);

  dim3 mgrid((NE / 16 + TPB - 1) / TPB, NT);
  const int rblocks = (NN + 3) / 4;
  const int gblocks = ((NN / 16 + 1) / 2 + 3) / 4;
  for (int s = 0; s < 3; ++s) {
    msg_mfma_kernel<<<mgrid, 256, 0, stream>>>(sbf, esrc, perm, wswz, msgb, msgs, 0);
    reduce_kernel<<<rblocks, 256, 0, stream>>>(msgs, row_ptr, agg);
    gru_mfma_kernel<4><<<gblocks, 256, 0, stream>>>(agg, ibf, sbf, w0ih, w0hh,
                                                    g0bih, g0bhh, states, sbf);
  }
  readout_kernel<<<rblocks, 256, 0, stream>>>(states, n2e, r1w, r1b, out, 0);

  for (int s = 0; s < 3; ++s) {
    msg_mfma_kernel<<<mgrid, 256, 0, stream>>>(sbf, esrc, perm, wswz, msgb, msgs, 1);
    reduce_kernel<<<rblocks, 256, 0, stream>>>(msgs, row_ptr, agg);
    gru_mfma_kernel<8><<<gblocks, 256, 0, stream>>>(agg, ibf, sbf, w1ih, w1hh,
                                                    g1bih, g1bhh, states, sbf);
  }
  readout_kernel<<<rblocks, 256, 0, stream>>>(states, n2e, r2w, r2b, out, HH);
}

// Round 5
// 773.321 us; speedup vs baseline: 6.8599x; 1.2957x over previous
//
#include <hip/hip_runtime.h>
#include <hip/hip_bf16.h>

#define NN 50000
#define NE 30000
#define NT 8
#define HH 128
#define NB 64
#define CONT 96
#define TPB 16
#define EDGES (NT * NE)
#define SBLK 512
#define SNB ((NN + SBLK - 1) / SBLK)   // 98
#define RCH 8                          // readout chunks per example

typedef __attribute__((ext_vector_type(8))) short short8;
typedef __attribute__((ext_vector_type(4))) float f32x4;

__device__ __forceinline__ float sigm(float x) { return 1.f / (1.f + __expf(-x)); }
__device__ __forceinline__ unsigned short bfbits(float x) {
  __hip_bfloat16 b = __float2bfloat16(x);
  return *(unsigned short*)&b;
}

// ---------------------------------------------------------------- init
__global__ __launch_bounds__(256) void init_kernel(
    const int* __restrict__ cid, const int* __restrict__ tg,
    const float* __restrict__ ctab, const float* __restrict__ ttab,
    float* __restrict__ states,
    __hip_bfloat16* __restrict__ sbf, __hip_bfloat16* __restrict__ ibf)
{
  int i = blockIdx.x * 256 + threadIdx.x;
  if (i >= NN * HH) return;
  int n = i >> 7, d = i & 127;
  float v;
  if (d < CONT) v = ctab[(size_t)cid[n] * CONT + d];
  else          v = ttab[(size_t)tg[n] * 32 + (d - CONT)];
  states[i] = v;
  sbf[i]    = __float2bfloat16(v);
  ibf[i]    = __float2bfloat16(v);
}

// ---------------------------------------------------------------- CSR build
__global__ __launch_bounds__(256) void hist_kernel(
    const int* __restrict__ etgt, int* __restrict__ cnt)
{
  int i = blockIdx.x * 256 + threadIdx.x;
  if (i >= EDGES) return;
  atomicAdd(&cnt[etgt[i]], 1);
}

__global__ __launch_bounds__(SBLK) void scanA_kernel(
    const int* __restrict__ cnt, int* __restrict__ row_ptr, int* __restrict__ bsum)
{
  __shared__ int sm[SBLK];
  const int tid = threadIdx.x;
  const int i = blockIdx.x * SBLK + tid;
  int v = (i < NN) ? cnt[i] : 0;
  sm[tid] = v;
  __syncthreads();
  for (int off = 1; off < SBLK; off <<= 1) {
    int t = (tid >= off) ? sm[tid - off] : 0;
    __syncthreads();
    sm[tid] += t;
    __syncthreads();
  }
  if (i < NN) row_ptr[i] = sm[tid] - v;
  if (tid == SBLK - 1) bsum[blockIdx.x] = sm[tid];
}

__global__ __launch_bounds__(128) void scanB_kernel(
    const int* __restrict__ bsum, int* __restrict__ boff, int* __restrict__ row_ptr)
{
  __shared__ int sm[128];
  const int tid = threadIdx.x;
  int v = (tid < SNB) ? bsum[tid] : 0;
  sm[tid] = v;
  __syncthreads();
  for (int off = 1; off < 128; off <<= 1) {
    int t = (tid >= off) ? sm[tid - off] : 0;
    __syncthreads();
    sm[tid] += t;
    __syncthreads();
  }
  if (tid < SNB) boff[tid] = sm[tid] - v;
  if (tid == 127) row_ptr[NN] = sm[127];
}

__global__ __launch_bounds__(SBLK) void scanC_kernel(
    int* __restrict__ row_ptr, int* __restrict__ cnt2, const int* __restrict__ boff)
{
  int i = blockIdx.x * SBLK + threadIdx.x;
  if (i >= NN) return;
  int r = row_ptr[i] + boff[blockIdx.x];
  row_ptr[i] = r;
  cnt2[i] = r;
}

__global__ __launch_bounds__(256) void scatter_kernel(
    const int* __restrict__ etgt, int* __restrict__ cnt2, int* __restrict__ perm)
{
  int i = blockIdx.x * 256 + threadIdx.x;
  if (i >= EDGES) return;
  perm[i] = atomicAdd(&cnt2[etgt[i]], 1);
}

// example boundaries from sorted n2e: ebnd[ex] = first n with n2e[n] >= ex
__global__ __launch_bounds__(128) void exbound_kernel(
    const int* __restrict__ n2e, int* __restrict__ ebnd)
{
  int ex = threadIdx.x;
  if (ex > NB) return;
  int lo = 0, hi = NN;
  while (lo < hi) { int mid = (lo + hi) >> 1; if (n2e[mid] < ex) lo = mid + 1; else hi = mid; }
  ebnd[ex] = lo;
}

// ---------------------------------------------------------------- all weight swizzles (one launch)
__device__ __forceinline__ void gru_swz_one(
    const float* __restrict__ W, __hip_bfloat16* __restrict__ out, int KSL, int mode, int i)
{
  int j = i & 7, lane = (i >> 3) & 63, kk = (i >> 9) % KSL, nt = i / (KSL * 512);
  int hi = lane >> 4, lo = lane & 15;
  int p = kk * 32 + hi * 8 + j;
  int k;
  if (mode == 0)      k = p;
  else if (mode == 1) k = (p & 7) * 16 + (p >> 3);
  else                k = (p < 128) ? p : 128 + ((p - 128) & 7) * 16 + ((p - 128) >> 3);
  out[i] = __float2bfloat16(W[(size_t)k * 384 + nt * 16 + lo]);
}

__global__ __launch_bounds__(256) void wswz_all_kernel(
    const float* __restrict__ msgW, __hip_bfloat16* __restrict__ wswz,
    const float* __restrict__ g0Wih, __hip_bfloat16* __restrict__ w0ih,
    const float* __restrict__ g0Whh, __hip_bfloat16* __restrict__ w0hh,
    const float* __restrict__ g1Wih, __hip_bfloat16* __restrict__ w1ih,
    const float* __restrict__ g1Whh, __hip_bfloat16* __restrict__ w1hh)
{
  int i = blockIdx.x * 256 + threadIdx.x;   // 507904 total
  if (i < 262144) {
    int j = i & 7, lane = (i >> 3) & 63, kk = (i >> 9) & 3, nt = (i >> 11) & 7, lt = i >> 14;
    int hi = lane >> 4, lo = lane & 15;
    int k = kk * 32 + hi * 8 + j;
    wswz[i] = __float2bfloat16(msgW[((size_t)lt * HH + k) * HH + nt * 16 + lo]);
    return;
  }
  i -= 262144;
  if (i < 49152)  { gru_swz_one(g0Wih, w0ih, 4, 1, i); return; }
  i -= 49152;
  if (i < 49152)  { gru_swz_one(g0Whh, w0hh, 4, 0, i); return; }
  i -= 49152;
  if (i < 98304)  { gru_swz_one(g1Wih, w1ih, 8, 2, i); return; }
  i -= 98304;
  if (i < 49152)  { gru_swz_one(g1Whh, w1hh, 4, 0, i); return; }
}

// ---------------------------------------------------------------- messages (MFMA, no atomics)
__global__ __launch_bounds__(256) void msg_mfma_kernel(
    const __hip_bfloat16* __restrict__ sbf, const int* __restrict__ esrc,
    const int* __restrict__ perm, const __hip_bfloat16* __restrict__ wswz,
    const float* __restrict__ ball, __hip_bfloat16* __restrict__ msgs, int layer)
{
  __shared__ short8 Wl[8 * 4 * 64];  // 32KB
  const int t = blockIdx.y;
  {
    const float4* wg = (const float4*)(wswz + (size_t)(layer * NT + t) * 16384);
    float4* wl = (float4*)Wl;
    for (int i = threadIdx.x; i < 2048; i += 256) wl[i] = wg[i];
  }
  const int lane = threadIdx.x & 63;
  const int wv   = threadIdx.x >> 6;
  const int hi = lane >> 4, lo = lane & 15;
  float bias_v[8];
#pragma unroll
  for (int nt = 0; nt < 8; ++nt)
    bias_v[nt] = ball[(layer * NT + t) * HH + nt * 16 + lo];
  __syncthreads();

  const int tile_end = min((int)(blockIdx.x + 1) * TPB, NE / 16);
  for (int tile = blockIdx.x * TPB + wv; tile < tile_end; tile += 4) {
    const int e0 = tile * 16;
    const int src = esrc[t * NE + e0 + lo];
    const short* srow = (const short*)(sbf + (size_t)src * HH);
    short8 a[4];
#pragma unroll
    for (int kk = 0; kk < 4; ++kk)
      a[kk] = *(const short8*)(srow + kk * 32 + hi * 8);
    int slot[4];
#pragma unroll
    for (int r = 0; r < 4; ++r) slot[r] = perm[t * NE + e0 + hi * 4 + r];
    f32x4 acc[8];
#pragma unroll
    for (int nt = 0; nt < 8; ++nt) acc[nt] = (f32x4){0.f, 0.f, 0.f, 0.f};
#pragma unroll
    for (int nt = 0; nt < 8; ++nt)
#pragma unroll
      for (int kk = 0; kk < 4; ++kk)
        acc[nt] = __builtin_amdgcn_mfma_f32_16x16x32_bf16(
            a[kk], Wl[(nt * 4 + kk) * 64 + lane], acc[nt], 0, 0, 0);
#pragma unroll
    for (int r = 0; r < 4; ++r) {
      short8 m;
#pragma unroll
      for (int nt = 0; nt < 8; ++nt)
        ((unsigned short*)&m)[nt] = bfbits(acc[nt][r] + bias_v[nt]);
      *(short8*)((short*)msgs + (size_t)slot[r] * HH + lo * 8) = m;
    }
  }
}

// ---------------------------------------------------------------- reduce (CSR gather-sum)
__global__ __launch_bounds__(256) void reduce_kernel(
    const __hip_bfloat16* __restrict__ msgs, const int* __restrict__ row_ptr,
    __hip_bfloat16* __restrict__ agg)
{
  const int lane = threadIdx.x & 63;
  const int n = blockIdx.x * 4 + (threadIdx.x >> 6);
  if (n >= NN) return;
  const int b = row_ptr[n], e = row_ptr[n + 1];
  float a0 = 0.f, a1 = 0.f;
  for (int i = b; i < e; ++i) {
    unsigned int v = *(const unsigned int*)((const short*)msgs + (size_t)i * HH + lane * 2);
    a0 += __uint_as_float(v << 16);
    a1 += __uint_as_float(v & 0xffff0000u);
  }
  unsigned int o = ((unsigned int)bfbits(a1) << 16) | bfbits(a0);
  *(unsigned int*)((short*)agg + (size_t)n * HH + lane * 2) = o;
}

// ---------------------------------------------------------------- GRU (MFMA, 2 tiles/wave)
template <int KSL>
__global__ __launch_bounds__(256) void gru_mfma_kernel(
    const __hip_bfloat16* __restrict__ agg,
    const __hip_bfloat16* __restrict__ ibf,
    const __hip_bfloat16* __restrict__ hbf,
    const __hip_bfloat16* __restrict__ Wih_s,
    const __hip_bfloat16* __restrict__ Whh_s,
    const float* __restrict__ bih, const float* __restrict__ bhh,
    float* __restrict__ states, __hip_bfloat16* __restrict__ sbf_out)
{
  const int lane = threadIdx.x & 63;
  const int wv   = threadIdx.x >> 6;
  const int NTILE = NN / 16;          // 3125
  const int t0 = (blockIdx.x * 4 + wv) * 2;
  if (t0 >= NTILE) return;
  const bool two = (t0 + 1 < NTILE);
  const int hi = lane >> 4, lo = lane & 15;

  short8 ax[2][KSL], ah[2][4];
#pragma unroll
  for (int u = 0; u < 2; ++u) {
    const int nb = (u == 0 || two) ? (t0 + u) * 16 : t0 * 16;
    const short* arow = (const short*)(agg + (size_t)(nb + lo) * HH);
    const short* hrow = (const short*)(hbf + (size_t)(nb + lo) * HH);
    if (KSL == 8) {
      const short* irow = (const short*)(ibf + (size_t)(nb + lo) * HH);
#pragma unroll
      for (int kk = 0; kk < 4; ++kk) {
        ax[u][kk]     = *(const short8*)(irow + kk * 32 + hi * 8);
        ax[u][kk + 4] = *(const short8*)(arow + kk * 32 + hi * 8);
      }
    } else {
#pragma unroll
      for (int kk = 0; kk < 4; ++kk)
        ax[u][kk] = *(const short8*)(arow + kk * 32 + hi * 8);
    }
#pragma unroll
    for (int kk = 0; kk < 4; ++kk)
      ah[u][kk] = *(const short8*)(hrow + kk * 32 + hi * 8);
  }

  const short8* Bih = (const short8*)Wih_s;
  const short8* Bhh = (const short8*)Whh_s;

#pragma unroll
  for (int dt = 0; dt < 8; ++dt) {
    f32x4 gi[2][3], gh[2][3];
#pragma unroll
    for (int u = 0; u < 2; ++u)
#pragma unroll
      for (int g = 0; g < 3; ++g) {
        gi[u][g] = (f32x4){0.f, 0.f, 0.f, 0.f};
        gh[u][g] = (f32x4){0.f, 0.f, 0.f, 0.f};
      }
#pragma unroll
    for (int kk = 0; kk < KSL; ++kk)
#pragma unroll
      for (int g = 0; g < 3; ++g) {
        short8 b = Bih[((size_t)(dt + 8 * g) * KSL + kk) * 64 + lane];
        gi[0][g] = __builtin_amdgcn_mfma_f32_16x16x32_bf16(ax[0][kk], b, gi[0][g], 0, 0, 0);
        gi[1][g] = __builtin_amdgcn_mfma_f32_16x16x32_bf16(ax[1][kk], b, gi[1][g], 0, 0, 0);
      }
#pragma unroll
    for (int kk = 0; kk < 4; ++kk)
#pragma unroll
      for (int g = 0; g < 3; ++g) {
        short8 b = Bhh[((size_t)(dt + 8 * g) * 4 + kk) * 64 + lane];
        gh[0][g] = __builtin_amdgcn_mfma_f32_16x16x32_bf16(ah[0][kk], b, gh[0][g], 0, 0, 0);
        gh[1][g] = __builtin_amdgcn_mfma_f32_16x16x32_bf16(ah[1][kk], b, gh[1][g], 0, 0, 0);
      }
    const int c = dt * 16 + lo;
    const float bir = bih[c], biz = bih[c + 128], bin = bih[c + 256];
    const float bhr = bhh[c], bhz = bhh[c + 128], bhn = bhh[c + 256];
    const int uend = two ? 2 : 1;
    for (int u = 0; u < uend; ++u) {
      const int nb = (t0 + u) * 16;
#pragma unroll
      for (int r = 0; r < 4; ++r) {
        const int node = nb + hi * 4 + r;
        const float rg = sigm(gi[u][0][r] + bir + gh[u][0][r] + bhr);
        const float zg = sigm(gi[u][1][r] + biz + gh[u][1][r] + bhz);
        const float ng = tanhf(gi[u][2][r] + bin + rg * (gh[u][2][r] + bhn));
        const float hc = states[(size_t)node * HH + c];
        const float hn2 = (1.f - zg) * ng + zg * hc;
        states[(size_t)node * HH + c] = hn2;
        sbf_out[(size_t)node * HH + c] = __float2bfloat16(hn2);
      }
    }
  }
}

// ---------------------------------------------------------------- readout (segmented, low-contention)
// grid = NB * RCH blocks x 256. Waves accumulate g*s over strided nodes of ONE
// example; LDS-combine the 4 waves; one 128-wide atomic row per block.
__global__ __launch_bounds__(256) void readout_kernel(
    const float* __restrict__ states, const int* __restrict__ ebnd,
    const float* __restrict__ rw, const float* __restrict__ rb,
    float* __restrict__ out, int coff)
{
  __shared__ float sm[4][128];
  const int ex = blockIdx.x / RCH, ch = blockIdx.x % RCH;
  const int s = ebnd[ex], e = ebnd[ex + 1];
  const int lane = threadIdx.x & 63;
  const int wv   = threadIdx.x >> 6;
  const float w0 = rw[lane], w1 = rw[lane + 64], rbv = rb[0];
  float a0 = 0.f, a1 = 0.f;
  for (int n = s + ch * 4 + wv; n < e; n += 4 * RCH) {
    const float s0 = states[(size_t)n * HH + lane];
    const float s1 = states[(size_t)n * HH + lane + 64];
    float p = s0 * w0 + s1 * w1;
#pragma unroll
    for (int o = 32; o; o >>= 1) p += __shfl_xor(p, o, 64);
    const float g = sigm(p + rbv);
    a0 += g * s0;
    a1 += g * s1;
  }
  sm[wv][lane] = a0;
  sm[wv][lane + 64] = a1;
  __syncthreads();
  if (wv == 0) {
    float v0 = sm[0][lane] + sm[1][lane] + sm[2][lane] + sm[3][lane];
    float v1 = sm[0][lane + 64] + sm[1][lane + 64] + sm[2][lane + 64] + sm[3][lane + 64];
    atomicAdd(&out[(size_t)ex * (2 * HH) + coff + lane], v0);
    atomicAdd(&out[(size_t)ex * (2 * HH) + coff + lane + 64], v1);
  }
}

// ---------------------------------------------------------------- launch
extern "C" void kernel_launch(void* const* d_in, const int* in_sizes, int n_in,
                              void* d_out, int out_size, void* d_ws, size_t ws_size,
                              hipStream_t stream)
{
  const int*   cid   = (const int*)d_in[0];
  const int*   tg    = (const int*)d_in[1];
  const int*   esrc  = (const int*)d_in[2];
  const int*   etgt  = (const int*)d_in[3];
  const int*   n2e   = (const int*)d_in[4];
  const float* ctab  = (const float*)d_in[5];
  const float* ttab  = (const float*)d_in[6];
  const float* msgW  = (const float*)d_in[7];
  const float* msgb  = (const float*)d_in[8];
  const float* g0Wih = (const float*)d_in[9];
  const float* g0Whh = (const float*)d_in[10];
  const float* g0bih = (const float*)d_in[11];
  const float* g0bhh = (const float*)d_in[12];
  const float* g1Wih = (const float*)d_in[13];
  const float* g1Whh = (const float*)d_in[14];
  const float* g1bih = (const float*)d_in[15];
  const float* g1bhh = (const float*)d_in[16];
  const float* r1w   = (const float*)d_in[17];
  const float* r1b   = (const float*)d_in[18];
  const float* r2w   = (const float*)d_in[19];
  const float* r2b   = (const float*)d_in[20];

  float* out    = (float*)d_out;
  float* states = (float*)d_ws;
  __hip_bfloat16* sbf  = (__hip_bfloat16*)(states + (size_t)NN * HH);
  __hip_bfloat16* ibf  = sbf + (size_t)NN * HH;
  __hip_bfloat16* agg  = ibf + (size_t)NN * HH;
  __hip_bfloat16* msgs = agg + (size_t)NN * HH;
  __hip_bfloat16* wswz = msgs + (size_t)EDGES * HH;
  __hip_bfloat16* w0ih = wswz + 262144;
  __hip_bfloat16* w0hh = w0ih + 24 * 4 * 512;
  __hip_bfloat16* w1ih = w0hh + 24 * 4 * 512;
  __hip_bfloat16* w1hh = w1ih + 24 * 8 * 512;
  int* row_ptr = (int*)(w1hh + 24 * 4 * 512);
  int* cnt     = row_ptr + NN + 1;
  int* cnt2    = cnt + NN;
  int* perm    = cnt2 + NN;
  int* bsum    = perm + EDGES;
  int* boff    = bsum + SNB;
  int* ebnd    = boff + SNB;

  hipMemsetAsync(d_out, 0, (size_t)NB * 2 * HH * sizeof(float), stream);
  hipMemsetAsync(cnt, 0, (size_t)NN * sizeof(int), stream);
  const int eblocks = (EDGES + 255) / 256;
  hist_kernel<<<eblocks, 256, 0, stream>>>(etgt, cnt);
  scanA_kernel<<<SNB, SBLK, 0, stream>>>(cnt, row_ptr, bsum);
  scanB_kernel<<<1, 128, 0, stream>>>(bsum, boff, row_ptr);
  scanC_kernel<<<SNB, SBLK, 0, stream>>>(row_ptr, cnt2, boff);
  scatter_kernel<<<eblocks, 256, 0, stream>>>(etgt, cnt2, perm);
  exbound_kernel<<<1, 128, 0, stream>>>(n2e, ebnd);

  wswz_all_kernel<<<507904 / 256, 256, 0, stream>>>(msgW, wswz, g0Wih, w0ih, g0Whh, w0hh,
                                                    g1Wih, w1ih, g1Whh, w1hh);
  init_kernel<<<(NN * HH + 255) / 256, 256, 0, stream>>>(cid, tg, ctab, ttab, states, sbf, ibf);

  dim3 mgrid((NE / 16 + TPB - 1) / TPB, NT);
  const int rblocks = (NN + 3) / 4;
  const int gblocks = ((NN / 16 + 1) / 2 + 3) / 4;
  for (int s = 0; s < 3; ++s) {
    msg_mfma_kernel<<<mgrid, 256, 0, stream>>>(sbf, esrc, perm, wswz, msgb, msgs, 0);
    reduce_kernel<<<rblocks, 256, 0, stream>>>(msgs, row_ptr, agg);
    gru_mfma_kernel<4><<<gblocks, 256, 0, stream>>>(agg, ibf, sbf, w0ih, w0hh,
                                                    g0bih, g0bhh, states, sbf);
  }
  readout_kernel<<<NB * RCH, 256, 0, stream>>>(states, ebnd, r1w, r1b, out, 0);

  for (int s = 0; s < 3; ++s) {
    msg_mfma_kernel<<<mgrid, 256, 0, stream>>>(sbf, esrc, perm, wswz, msgb, msgs, 1);
    reduce_kernel<<<rblocks, 256, 0, stream>>>(msgs, row_ptr, agg);
    gru_mfma_kernel<8><<<gblocks, 256, 0, stream>>>(agg, ibf, sbf, w1ih, w1hh,
                                                    g1bih, g1bhh, states, sbf);
  }
  readout_kernel<<<NB * RCH, 256, 0, stream>>>(states, ebnd, r2w, r2b, out, HH);
}